// Round 1
// baseline (600.778 us; speedup 1.0000x reference)
//
#include <hip/hip_runtime.h>
#include <math.h>

#define N_NODES 100000
#define E_EDGES 1600000
#define IN_DIM  128
#define FEAT    64
#define OUT_DIM 64

// ---------------- kernel 1: x = relu(h @ W1 + b1) ----------------
// block = 256 threads, 64 rows per block. W1 (128x64) + h tile (64x128, pad 132) in LDS.
__global__ __launch_bounds__(256) void gemm1_relu(
    const float* __restrict__ h, const float* __restrict__ W1,
    const float* __restrict__ b1, float* __restrict__ x)
{
    __shared__ float Ws[IN_DIM * FEAT];   // 32 KB, stride 64
    __shared__ float hs[64 * 132];        // ~33 KB, stride 132 (2-way max conflict)
    const int tid = threadIdx.x;
    const int r0  = blockIdx.x * 64;

    // load W1 (2048 float4)
    for (int i = tid; i < IN_DIM * FEAT / 4; i += 256)
        ((float4*)Ws)[i] = ((const float4*)W1)[i];
    // load h tile (2048 float4), zero-pad OOB rows
    for (int i = tid; i < 64 * IN_DIM / 4; i += 256) {
        int row = i >> 5;      // 32 float4 per row
        int c4  = i & 31;
        float4 v = make_float4(0.f, 0.f, 0.f, 0.f);
        if (r0 + row < N_NODES)
            v = ((const float4*)h)[(size_t)(r0 + row) * 32 + c4];
        *((float4*)&hs[row * 132 + c4 * 4]) = v;
    }
    __syncthreads();

    const int r  = tid >> 2;          // 0..63
    const int c0 = (tid & 3) * 16;    // 0,16,32,48
    float acc[16];
#pragma unroll
    for (int j = 0; j < 16; ++j) acc[j] = 0.f;

    for (int k = 0; k < IN_DIM; ++k) {
        float a = hs[r * 132 + k];
#pragma unroll
        for (int j = 0; j < 16; ++j)
            acc[j] = fmaf(a, Ws[k * FEAT + c0 + j], acc[j]);
    }
    if (r0 + r < N_NODES) {
#pragma unroll
        for (int j = 0; j < 16; ++j) {
            float v = acc[j] + b1[c0 + j];
            x[(size_t)(r0 + r) * FEAT + c0 + j] = v > 0.f ? v : 0.f;
        }
    }
}

// ---------------- kernel 2: in-degree count ----------------
__global__ __launch_bounds__(256) void deg_count(
    const int* __restrict__ dst, float* __restrict__ deg)
{
    int i = blockIdx.x * blockDim.x + threadIdx.x;
    int stride = gridDim.x * blockDim.x;
    for (; i < E_EDGES; i += stride)
        atomicAdd(&deg[dst[i]], 1.0f);
}

// ---------------- kernel 3: edge gate + scatter (layer 1 only) ----------------
// one wave per edge iteration; lane = feature index (0..63), head = lane>>4.
__global__ __launch_bounds__(256) void edge_aggregate(
    const float* __restrict__ x, const int* __restrict__ src,
    const int* __restrict__ dst, const float* __restrict__ deg,
    const float* __restrict__ gate_W, const float* __restrict__ gate_b,
    float* __restrict__ h0)
{
    const int lane   = threadIdx.x & 63;
    const int wave   = blockIdx.x * (blockDim.x >> 6) + (threadIdx.x >> 6);
    const int nwaves = gridDim.x * (blockDim.x >> 6);
    const int dd     = lane & 15;           // within-head dim
    // layer 1 gate: gate_W flat [2,32,1] -> offset 32; gate_b flat [2,1] -> [1]
    const float gd = gate_W[32 + dd];       // multiplies hd part
    const float gs = gate_W[32 + 16 + dd];  // multiplies hs part
    const float gb = gate_b[1];

    for (int e = wave; e < E_EDGES; e += nwaves) {
        int s = src[e];
        int d = dst[e];
        float hsv = x[(size_t)s * FEAT + lane];
        float hdv = x[(size_t)d * FEAT + lane];
        float en  = rsqrtf(fmaxf(deg[s], 1.f)) * rsqrtf(fmaxf(deg[d], 1.f));
        float p   = fmaf(hdv, gd, hsv * gs);
        // reduce within each 16-lane head group
        p += __shfl_xor(p, 1, 64);
        p += __shfl_xor(p, 2, 64);
        p += __shfl_xor(p, 4, 64);
        p += __shfl_xor(p, 8, 64);
        float sc = tanhf(p + gb) * en;
        atomicAdd(&h0[(size_t)d * FEAT + lane], hsv * sc);
    }
}

// ---------------- kernel 4: out = (0.5*x + h0) @ W2 + b2 ----------------
__global__ __launch_bounds__(256) void gemm2_out(
    const float* __restrict__ x, const float* __restrict__ h0,
    const float* __restrict__ W2, const float* __restrict__ b2,
    float* __restrict__ out)
{
    __shared__ float Ws[FEAT * OUT_DIM];  // 16 KB, stride 64
    __shared__ float ts[64 * 68];         // ~17 KB, stride 68
    const int tid = threadIdx.x;
    const int r0  = blockIdx.x * 64;

    for (int i = tid; i < FEAT * OUT_DIM / 4; i += 256)
        ((float4*)Ws)[i] = ((const float4*)W2)[i];
    for (int i = tid; i < 64 * FEAT / 4; i += 256) {
        int row = i >> 4;     // 16 float4 per row
        int c4  = i & 15;
        float4 v = make_float4(0.f, 0.f, 0.f, 0.f);
        if (r0 + row < N_NODES) {
            float4 a = ((const float4*)x)[(size_t)(r0 + row) * 16 + c4];
            float4 b = ((const float4*)h0)[(size_t)(r0 + row) * 16 + c4];
            v = make_float4(fmaf(0.5f, a.x, b.x), fmaf(0.5f, a.y, b.y),
                            fmaf(0.5f, a.z, b.z), fmaf(0.5f, a.w, b.w));
        }
        *((float4*)&ts[row * 68 + c4 * 4]) = v;
    }
    __syncthreads();

    const int r  = tid >> 2;
    const int c0 = (tid & 3) * 16;
    float acc[16];
#pragma unroll
    for (int j = 0; j < 16; ++j) acc[j] = 0.f;

    for (int k = 0; k < FEAT; ++k) {
        float a = ts[r * 68 + k];
#pragma unroll
        for (int j = 0; j < 16; ++j)
            acc[j] = fmaf(a, Ws[k * OUT_DIM + c0 + j], acc[j]);
    }
    if (r0 + r < N_NODES) {
#pragma unroll
        for (int j = 0; j < 16; ++j)
            out[(size_t)(r0 + r) * OUT_DIM + c0 + j] = acc[j] + b2[c0 + j];
    }
}

extern "C" void kernel_launch(void* const* d_in, const int* in_sizes, int n_in,
                              void* d_out, int out_size, void* d_ws, size_t ws_size,
                              hipStream_t stream)
{
    const float* h   = (const float*)d_in[0];
    const int*   src = (const int*)d_in[1];
    const int*   dst = (const int*)d_in[2];
    const float* W1  = (const float*)d_in[3];
    const float* b1  = (const float*)d_in[4];
    const float* W2  = (const float*)d_in[5];
    const float* b2  = (const float*)d_in[6];
    const float* gW  = (const float*)d_in[7];
    const float* gb  = (const float*)d_in[8];
    float* out = (float*)d_out;

    // workspace layout (fp32): x[N*64] | h0[N*64] | deg[N]
    float* x   = (float*)d_ws;
    float* h0  = x  + (size_t)N_NODES * FEAT;
    float* deg = h0 + (size_t)N_NODES * FEAT;

    // zero h0 + deg in one contiguous memset (ws is poisoned 0xAA each call)
    hipMemsetAsync(h0, 0, ((size_t)N_NODES * FEAT + N_NODES) * sizeof(float), stream);

    gemm1_relu<<<(N_NODES + 63) / 64, 256, 0, stream>>>(h, W1, b1, x);
    deg_count<<<1024, 256, 0, stream>>>(dst, deg);
    edge_aggregate<<<2048, 256, 0, stream>>>(x, src, dst, deg, gW, gb, h0);
    gemm2_out<<<(N_NODES + 63) / 64, 256, 0, stream>>>(x, h0, W2, b2, out);
}

// Round 2
// 545.229 us; speedup vs baseline: 1.1019x; 1.1019x over previous
//
#include <hip/hip_runtime.h>
#include <math.h>

#define N_NODES 100000
#define E_EDGES 1600000
#define IN_DIM  128
#define FEAT    64
#define OUT_DIM 64
#define SCAN_B  256
#define NBLK    ((N_NODES + SCAN_B - 1) / SCAN_B)   // 391

// ---------------- kernel: in-degree count (int) ----------------
__global__ __launch_bounds__(256) void k_deg(
    const int* __restrict__ dst, int* __restrict__ deg)
{
    int i = blockIdx.x * blockDim.x + threadIdx.x;
    int stride = gridDim.x * blockDim.x;
    for (; i < E_EDGES; i += stride)
        atomicAdd(&deg[dst[i]], 1);
}

// ---------------- scan stage 1: per-block exclusive scan ----------------
__global__ __launch_bounds__(SCAN_B) void k_scan1(
    const int* __restrict__ deg, int* __restrict__ rowptr, int* __restrict__ blocksum)
{
    __shared__ int tmp[SCAN_B];
    int t = threadIdx.x;
    int i = blockIdx.x * SCAN_B + t;
    int v = (i < N_NODES) ? deg[i] : 0;
    tmp[t] = v;
    __syncthreads();
    for (int off = 1; off < SCAN_B; off <<= 1) {
        int add = (t >= off) ? tmp[t - off] : 0;
        __syncthreads();
        tmp[t] += add;
        __syncthreads();
    }
    if (i < N_NODES) rowptr[i] = tmp[t] - v;      // exclusive (local)
    if (t == SCAN_B - 1) blocksum[blockIdx.x] = tmp[t];
}

// ---------------- scan stage 2: scan of block sums (single block) ----------------
__global__ __launch_bounds__(512) void k_scan2(
    const int* __restrict__ blocksum, int* __restrict__ blockbase, int* __restrict__ rowptr)
{
    __shared__ int tmp[512];
    int t = threadIdx.x;
    int v = (t < NBLK) ? blocksum[t] : 0;
    tmp[t] = v;
    __syncthreads();
    for (int off = 1; off < 512; off <<= 1) {
        int add = (t >= off) ? tmp[t - off] : 0;
        __syncthreads();
        tmp[t] += add;
        __syncthreads();
    }
    if (t < NBLK) blockbase[t] = tmp[t] - v;      // exclusive
    if (t == 0) rowptr[N_NODES] = E_EDGES;
}

// ---------------- scan stage 3: add base, init cursor ----------------
__global__ __launch_bounds__(256) void k_scan3(
    int* __restrict__ rowptr, const int* __restrict__ blockbase, int* __restrict__ cursor)
{
    int i = blockIdx.x * blockDim.x + threadIdx.x;
    if (i < N_NODES) {
        int r = rowptr[i] + blockbase[i >> 8];    // 256 per scan1 block
        rowptr[i] = r;
        cursor[i] = r;
    }
}

// ---------------- scatter edges into CSR slots ----------------
__global__ __launch_bounds__(256) void k_scatter(
    const int* __restrict__ src, const int* __restrict__ dst,
    int* __restrict__ cursor, int* __restrict__ src_sorted)
{
    int i = blockIdx.x * blockDim.x + threadIdx.x;
    int stride = gridDim.x * blockDim.x;
    for (; i < E_EDGES; i += stride) {
        int d = dst[i];
        int pos = atomicAdd(&cursor[d], 1);
        src_sorted[pos] = src[i];
    }
}

// ---------------- gemm1: xs2 = relu(h@W1+b1)*norm, proj = gate projections ----------------
__global__ __launch_bounds__(256) void gemm1_relu(
    const float* __restrict__ h, const float* __restrict__ W1,
    const float* __restrict__ b1, const int* __restrict__ deg,
    const float* __restrict__ gate_W,
    float* __restrict__ xs2, float* __restrict__ proj)
{
    __shared__ float Ws[IN_DIM * FEAT];   // 32 KB
    __shared__ float hs[64 * 132];        // ~33 KB, pad 132
    const int tid = threadIdx.x;
    const int r0  = blockIdx.x * 64;

    for (int i = tid; i < IN_DIM * FEAT / 4; i += 256)
        ((float4*)Ws)[i] = ((const float4*)W1)[i];
    for (int i = tid; i < 64 * IN_DIM / 4; i += 256) {
        int row = i >> 5;
        int c4  = i & 31;
        float4 v = make_float4(0.f, 0.f, 0.f, 0.f);
        if (r0 + row < N_NODES)
            v = ((const float4*)h)[(size_t)(r0 + row) * 32 + c4];
        *((float4*)&hs[row * 132 + c4 * 4]) = v;
    }
    __syncthreads();

    const int r    = tid >> 2;          // 0..63
    const int head = tid & 3;           // this thread's 16 cols = one head
    const int c0   = head * 16;
    float acc[16];
#pragma unroll
    for (int j = 0; j < 16; ++j) acc[j] = 0.f;

    for (int k = 0; k < IN_DIM; ++k) {
        float a = hs[r * 132 + k];
#pragma unroll
        for (int j = 0; j < 16; ++j)
            acc[j] = fmaf(a, Ws[k * FEAT + c0 + j], acc[j]);
    }
    if (r0 + r < N_NODES) {
        int   n  = r0 + r;
        float nr = rsqrtf(fmaxf((float)deg[n], 1.f));
        float xa = 0.f, xb = 0.f;
#pragma unroll
        for (int j = 0; j < 16; ++j) {
            float v = acc[j] + b1[c0 + j];
            v = v > 0.f ? v : 0.f;
            // gate layer 1: gd = gW[32+j] (dst part), gs = gW[48+j] (src part)
            xa = fmaf(v, gate_W[32 + j], xa);
            xb = fmaf(v, gate_W[48 + j], xb);
            xs2[(size_t)n * FEAT + c0 + j] = v * nr;
        }
        proj[(size_t)n * 8 + head]     = xa;   // dst-side a
        proj[(size_t)n * 8 + 4 + head] = xb;   // src-side b
    }
}

// ---------------- fused dst-centric aggregate + gemm2 ----------------
// one wave per node; lane = feature 0..63, head = lane>>4
__global__ __launch_bounds__(256) void k_aggregate_out(
    const float* __restrict__ xs2, const float* __restrict__ proj,
    const int* __restrict__ rowptr, const int* __restrict__ src_sorted,
    const int* __restrict__ deg, const float* __restrict__ gate_b,
    const float* __restrict__ W2, const float* __restrict__ b2,
    float* __restrict__ out)
{
    __shared__ float W2s[FEAT * OUT_DIM];   // 16 KB
    const int tid = threadIdx.x;
    for (int i = tid; i < FEAT * OUT_DIM / 4; i += 256)
        ((float4*)W2s)[i] = ((const float4*)W2)[i];
    __syncthreads();

    const int lane   = tid & 63;
    const int head   = lane >> 4;
    const int wave   = blockIdx.x * (blockDim.x >> 6) + (tid >> 6);
    const int nwaves = gridDim.x * (blockDim.x >> 6);
    const float gb   = gate_b[1];
    const float b2v  = b2[lane];

    for (int n = wave; n < N_NODES; n += nwaves) {
        int beg = rowptr[n];
        int end = rowptr[n + 1];
        float a_d = proj[(size_t)n * 8 + head] + gb;
        float acc = 0.f;
        for (int j = beg; j < end; ++j) {
            int   s   = src_sorted[j];
            float xsv = xs2[(size_t)s * FEAT + lane];
            float bh  = proj[(size_t)s * 8 + 4 + head];
            float t   = tanhf(a_d + bh);
            acc = fmaf(t, xsv, acc);
        }
        float sd = sqrtf(fmaxf((float)deg[n], 1.f));   // 1/norm[n]
        float nd = 1.f / sd;
        // v = 0.5*x[n] + norm[n]*sum ; x[n] = xs2[n]*sd
        float v = fmaf(0.5f * sd, xs2[(size_t)n * FEAT + lane], acc * nd);
        // out[n] = v @ W2 + b2 via lane broadcast
        float o = b2v;
#pragma unroll 8
        for (int k = 0; k < FEAT; ++k) {
            float vk = __shfl(v, k, 64);
            o = fmaf(vk, W2s[k * OUT_DIM + lane], o);
        }
        out[(size_t)n * OUT_DIM + lane] = o;
    }
}

extern "C" void kernel_launch(void* const* d_in, const int* in_sizes, int n_in,
                              void* d_out, int out_size, void* d_ws, size_t ws_size,
                              hipStream_t stream)
{
    const float* h   = (const float*)d_in[0];
    const int*   src = (const int*)d_in[1];
    const int*   dst = (const int*)d_in[2];
    const float* W1  = (const float*)d_in[3];
    const float* b1  = (const float*)d_in[4];
    const float* W2  = (const float*)d_in[5];
    const float* b2  = (const float*)d_in[6];
    const float* gW  = (const float*)d_in[7];
    const float* gb  = (const float*)d_in[8];
    float* out = (float*)d_out;

    // ws layout: xs2[N*64] f32 | proj[N*8] f32 | deg[N] i32 | rowptr[N+1] i32 |
    //            cursor[N] i32 | src_sorted[E] i32 | blocksum[512] | blockbase[512]
    float* xs2       = (float*)d_ws;
    float* proj      = xs2 + (size_t)N_NODES * FEAT;
    int*   deg       = (int*)(proj + (size_t)N_NODES * 8);
    int*   rowptr    = deg + N_NODES;
    int*   cursor    = rowptr + (N_NODES + 1);
    int*   src_sorted= cursor + N_NODES;
    int*   blocksum  = src_sorted + E_EDGES;
    int*   blockbase = blocksum + 512;

    hipMemsetAsync(deg, 0, N_NODES * sizeof(int), stream);

    k_deg   <<<1024, 256, 0, stream>>>(dst, deg);
    k_scan1 <<<NBLK, SCAN_B, 0, stream>>>(deg, rowptr, blocksum);
    k_scan2 <<<1, 512, 0, stream>>>(blocksum, blockbase, rowptr);
    k_scan3 <<<NBLK, 256, 0, stream>>>(rowptr, blockbase, cursor);
    gemm1_relu<<<(N_NODES + 63) / 64, 256, 0, stream>>>(h, W1, b1, deg, gW, xs2, proj);
    k_scatter<<<1024, 256, 0, stream>>>(src, dst, cursor, src_sorted);
    k_aggregate_out<<<2048, 256, 0, stream>>>(xs2, proj, rowptr, src_sorted,
                                              deg, gb, W2, b2, out);
}

// Round 3
// 472.079 us; speedup vs baseline: 1.2726x; 1.1550x over previous
//
#include <hip/hip_runtime.h>
#include <math.h>

#define N_NODES 100000
#define E_EDGES 1600000
#define IN_DIM  128
#define FEAT    64
#define OUT_DIM 64
#define SCAN_B  256
#define NBLK    ((N_NODES + SCAN_B - 1) / SCAN_B)   // 391
#define G1_ROWS 256
#define G1B     ((N_NODES + G1_ROWS - 1) / G1_ROWS) // 391
#define SCB     1024                                 // scatter blocks in merged kernel

// ---------------- in-degree count ----------------
__global__ __launch_bounds__(256) void k_deg(
    const int* __restrict__ dst, int* __restrict__ deg)
{
    int i = blockIdx.x * blockDim.x + threadIdx.x;
    int stride = gridDim.x * blockDim.x;
    for (; i < E_EDGES; i += stride)
        atomicAdd(&deg[dst[i]], 1);
}

// ---------------- scan stage 1 ----------------
__global__ __launch_bounds__(SCAN_B) void k_scan1(
    const int* __restrict__ deg, int* __restrict__ rowptr, int* __restrict__ blocksum)
{
    __shared__ int tmp[SCAN_B];
    int t = threadIdx.x;
    int i = blockIdx.x * SCAN_B + t;
    int v = (i < N_NODES) ? deg[i] : 0;
    tmp[t] = v;
    __syncthreads();
    for (int off = 1; off < SCAN_B; off <<= 1) {
        int add = (t >= off) ? tmp[t - off] : 0;
        __syncthreads();
        tmp[t] += add;
        __syncthreads();
    }
    if (i < N_NODES) rowptr[i] = tmp[t] - v;
    if (t == SCAN_B - 1) blocksum[blockIdx.x] = tmp[t];
}

// ---------------- scan stage 2 ----------------
__global__ __launch_bounds__(512) void k_scan2(
    const int* __restrict__ blocksum, int* __restrict__ blockbase, int* __restrict__ rowptr)
{
    __shared__ int tmp[512];
    int t = threadIdx.x;
    int v = (t < NBLK) ? blocksum[t] : 0;
    tmp[t] = v;
    __syncthreads();
    for (int off = 1; off < 512; off <<= 1) {
        int add = (t >= off) ? tmp[t - off] : 0;
        __syncthreads();
        tmp[t] += add;
        __syncthreads();
    }
    if (t < NBLK) blockbase[t] = tmp[t] - v;
    if (t == 0) rowptr[N_NODES] = E_EDGES;
}

// ---------------- scan stage 3: finalize rowptr, init cursor ----------------
__global__ __launch_bounds__(256) void k_scan3(
    int* __restrict__ rowptr, const int* __restrict__ blockbase, int* __restrict__ cursor)
{
    int i = blockIdx.x * blockDim.x + threadIdx.x;
    if (i < N_NODES) {
        int r = rowptr[i] + blockbase[i >> 8];
        rowptr[i] = r;
        cursor[i] = r;
    }
}

// ---------------- merged: gemm1 (reg-tiled) + CSR scatter ----------------
// blocks [0,SCB): scatter edges. blocks [SCB, SCB+G1B): gemm1 over 256 rows each.
__global__ __launch_bounds__(256, 2) void k_gemm1_scatter(
    const float* __restrict__ h, const float* __restrict__ W1,
    const float* __restrict__ b1, const int* __restrict__ deg,
    const float* __restrict__ gate_W,
    const int* __restrict__ src, const int* __restrict__ dst,
    int* __restrict__ cursor, int* __restrict__ src_sorted,
    float* __restrict__ xs2, float* __restrict__ proj)
{
    __shared__ float Ws[IN_DIM * FEAT];   // 32 KB, Ws[k*64+c]
    __shared__ float hT[16 * 260];        // 16.25 KB, hT[kk*260 + row], transposed tile
    const int tid = threadIdx.x;

    if (blockIdx.x < SCB) {
        int i = blockIdx.x * 256 + tid;
        for (; i < E_EDGES; i += SCB * 256) {
            int d = dst[i];
            int pos = atomicAdd(&cursor[d], 1);
            src_sorted[pos] = src[i];
        }
        return;
    }

    const int r0 = (blockIdx.x - SCB) * G1_ROWS;
    for (int i = tid; i < IN_DIM * FEAT / 4; i += 256)
        ((float4*)Ws)[i] = ((const float4*)W1)[i];

    const int rg = tid >> 2;     // 0..63: row group (4 rows)
    const int cg = tid & 3;      // 0..3: col group == head
    const int c0 = cg * 16;
    float acc[4][16];
#pragma unroll
    for (int i = 0; i < 4; ++i)
#pragma unroll
        for (int j = 0; j < 16; ++j) acc[i][j] = 0.f;

    const int  myrow = r0 + tid;
    const bool rok   = myrow < N_NODES;

    for (int kc = 0; kc < IN_DIM / 16; ++kc) {
        float4 f[4];
        if (rok) {
            const float4* hp = (const float4*)(h + (size_t)myrow * IN_DIM + kc * 16);
            f[0] = hp[0]; f[1] = hp[1]; f[2] = hp[2]; f[3] = hp[3];
        } else {
            f[0] = f[1] = f[2] = f[3] = make_float4(0.f, 0.f, 0.f, 0.f);
        }
        __syncthreads();   // previous iter's hT reads done
#pragma unroll
        for (int q = 0; q < 4; ++q) {
            hT[(q * 4 + 0) * 260 + tid] = f[q].x;
            hT[(q * 4 + 1) * 260 + tid] = f[q].y;
            hT[(q * 4 + 2) * 260 + tid] = f[q].z;
            hT[(q * 4 + 3) * 260 + tid] = f[q].w;
        }
        __syncthreads();
#pragma unroll
        for (int kk = 0; kk < 16; ++kk) {
            float4 a4 = *(const float4*)&hT[kk * 260 + rg * 4];
            const float* wrow = &Ws[(kc * 16 + kk) * FEAT + c0];
            float4 w0 = ((const float4*)wrow)[0];
            float4 w1 = ((const float4*)wrow)[1];
            float4 w2 = ((const float4*)wrow)[2];
            float4 w3 = ((const float4*)wrow)[3];
            const float a[4] = {a4.x, a4.y, a4.z, a4.w};
            const float w[16] = {w0.x, w0.y, w0.z, w0.w, w1.x, w1.y, w1.z, w1.w,
                                 w2.x, w2.y, w2.z, w2.w, w3.x, w3.y, w3.z, w3.w};
#pragma unroll
            for (int i = 0; i < 4; ++i)
#pragma unroll
                for (int j = 0; j < 16; ++j)
                    acc[i][j] = fmaf(a[i], w[j], acc[i][j]);
        }
    }

    // epilogue: bias + relu, gate projections, write xs2 = x*norm
#pragma unroll
    for (int i = 0; i < 4; ++i) {
        int r = r0 + rg * 4 + i;
        if (r >= N_NODES) continue;
        float nr = rsqrtf(fmaxf((float)deg[r], 1.f));
        float xa = 0.f, xb = 0.f;
        float vout[16];
#pragma unroll
        for (int j = 0; j < 16; ++j) {
            float v = acc[i][j] + b1[c0 + j];
            v = v > 0.f ? v : 0.f;
            xa = fmaf(v, gate_W[32 + j], xa);   // dst-side gate (within-head dim j)
            xb = fmaf(v, gate_W[48 + j], xb);   // src-side gate
            vout[j] = v * nr;
        }
        float* xp = &xs2[(size_t)r * FEAT + c0];
#pragma unroll
        for (int q = 0; q < 4; ++q)
            ((float4*)xp)[q] = make_float4(vout[q*4], vout[q*4+1], vout[q*4+2], vout[q*4+3]);
        proj[(size_t)r * 8 + cg]     = xa;
        proj[(size_t)r * 8 + 4 + cg] = xb;
    }
}

// ---------------- dst-centric aggregate: v = 0.5*x + norm*sum -> d_out ----------------
__global__ __launch_bounds__(256) void k_aggregate(
    const float* __restrict__ xs2, const float* __restrict__ proj,
    const int* __restrict__ rowptr, const int* __restrict__ src_sorted,
    const float* __restrict__ gate_b, float* __restrict__ v_out)
{
    const int tid    = threadIdx.x;
    const int lane   = tid & 63;
    const int head   = lane >> 4;
    const int wave   = blockIdx.x * 4 + (tid >> 6);
    const int nwaves = gridDim.x * 4;
    const float gb   = gate_b[1];

    for (int n = wave; n < N_NODES; n += nwaves) {
        int beg = rowptr[n];
        int end = rowptr[n + 1];
        float a_d = proj[(size_t)n * 8 + head] + gb;
        float acc = 0.f;
        if (beg < end) {
            int last = end - 1;
            int sA = __builtin_amdgcn_readfirstlane(src_sorted[beg]);
            int sB = __builtin_amdgcn_readfirstlane(src_sorted[min(beg + 1, last)]);
            float xsv = xs2[(size_t)sA * FEAT + lane];
            float bh  = proj[(size_t)sA * 8 + 4 + head];
            for (int j = beg; j < end; ++j) {
                int   sC    = __builtin_amdgcn_readfirstlane(src_sorted[min(j + 2, last)]);
                float xsv_n = xs2[(size_t)sB * FEAT + lane];
                float bh_n  = proj[(size_t)sB * 8 + 4 + head];
                // tanh(p) = 1 - 2/(exp2(p*2*log2e)+1); safe at +/-inf
                float e = __builtin_amdgcn_exp2f(2.8853900817779268f * (a_d + bh));
                float t = 1.f - 2.f * __builtin_amdgcn_rcpf(e + 1.f);
                acc = fmaf(t, xsv, acc);
                xsv = xsv_n; bh = bh_n; sB = sC;
            }
        }
        float dg = fmaxf((float)(end - beg), 1.f);
        float nd = rsqrtf(dg);          // norm[n]
        float sd = dg * nd;             // sqrt(deg) = 1/norm
        float v  = fmaf(0.5f * sd, xs2[(size_t)n * FEAT + lane], acc * nd);
        v_out[(size_t)n * FEAT + lane] = v;
    }
}

// ---------------- gemm2 in-place on d_out: out = v @ W2 + b2 ----------------
__global__ __launch_bounds__(256, 2) void k_gemm2(
    float* __restrict__ v, const float* __restrict__ W2, const float* __restrict__ b2)
{
    __shared__ float Ws[FEAT * OUT_DIM];  // 16 KB
    __shared__ float vT[16 * 260];        // 16.25 KB
    const int tid = threadIdx.x;
    const int r0  = blockIdx.x * G1_ROWS;

    for (int i = tid; i < FEAT * OUT_DIM / 4; i += 256)
        ((float4*)Ws)[i] = ((const float4*)W2)[i];

    const int rg = tid >> 2;
    const int cg = tid & 3;
    const int c0 = cg * 16;
    float acc[4][16];
#pragma unroll
    for (int i = 0; i < 4; ++i)
#pragma unroll
        for (int j = 0; j < 16; ++j) acc[i][j] = 0.f;

    const int  myrow = r0 + tid;
    const bool rok   = myrow < N_NODES;

    for (int kc = 0; kc < FEAT / 16; ++kc) {
        float4 f[4];
        if (rok) {
            const float4* vp = (const float4*)(v + (size_t)myrow * FEAT + kc * 16);
            f[0] = vp[0]; f[1] = vp[1]; f[2] = vp[2]; f[3] = vp[3];
        } else {
            f[0] = f[1] = f[2] = f[3] = make_float4(0.f, 0.f, 0.f, 0.f);
        }
        __syncthreads();
#pragma unroll
        for (int q = 0; q < 4; ++q) {
            vT[(q * 4 + 0) * 260 + tid] = f[q].x;
            vT[(q * 4 + 1) * 260 + tid] = f[q].y;
            vT[(q * 4 + 2) * 260 + tid] = f[q].z;
            vT[(q * 4 + 3) * 260 + tid] = f[q].w;
        }
        __syncthreads();
#pragma unroll
        for (int kk = 0; kk < 16; ++kk) {
            float4 a4 = *(const float4*)&vT[kk * 260 + rg * 4];
            const float* wrow = &Ws[(kc * 16 + kk) * OUT_DIM + c0];
            float4 w0 = ((const float4*)wrow)[0];
            float4 w1 = ((const float4*)wrow)[1];
            float4 w2 = ((const float4*)wrow)[2];
            float4 w3 = ((const float4*)wrow)[3];
            const float a[4] = {a4.x, a4.y, a4.z, a4.w};
            const float w[16] = {w0.x, w0.y, w0.z, w0.w, w1.x, w1.y, w1.z, w1.w,
                                 w2.x, w2.y, w2.z, w2.w, w3.x, w3.y, w3.z, w3.w};
#pragma unroll
            for (int i = 0; i < 4; ++i)
#pragma unroll
                for (int j = 0; j < 16; ++j)
                    acc[i][j] = fmaf(a[i], w[j], acc[i][j]);
        }
    }

#pragma unroll
    for (int i = 0; i < 4; ++i) {
        int r = r0 + rg * 4 + i;
        if (r >= N_NODES) continue;
        float* op = &v[(size_t)r * OUT_DIM + c0];
#pragma unroll
        for (int q = 0; q < 4; ++q) {
            float4 o = make_float4(acc[i][q*4]   + b2[c0 + q*4],
                                   acc[i][q*4+1] + b2[c0 + q*4 + 1],
                                   acc[i][q*4+2] + b2[c0 + q*4 + 2],
                                   acc[i][q*4+3] + b2[c0 + q*4 + 3]);
            ((float4*)op)[q] = o;
        }
    }
}

extern "C" void kernel_launch(void* const* d_in, const int* in_sizes, int n_in,
                              void* d_out, int out_size, void* d_ws, size_t ws_size,
                              hipStream_t stream)
{
    const float* h   = (const float*)d_in[0];
    const int*   src = (const int*)d_in[1];
    const int*   dst = (const int*)d_in[2];
    const float* W1  = (const float*)d_in[3];
    const float* b1  = (const float*)d_in[4];
    const float* W2  = (const float*)d_in[5];
    const float* b2  = (const float*)d_in[6];
    const float* gW  = (const float*)d_in[7];
    const float* gb  = (const float*)d_in[8];
    float* out = (float*)d_out;

    // ws: xs2[N*64] | proj[N*8] | deg | rowptr[N+1] | cursor | src_sorted[E] | blocksum | blockbase
    float* xs2        = (float*)d_ws;
    float* proj       = xs2 + (size_t)N_NODES * FEAT;
    int*   deg        = (int*)(proj + (size_t)N_NODES * 8);
    int*   rowptr     = deg + N_NODES;
    int*   cursor     = rowptr + (N_NODES + 1);
    int*   src_sorted = cursor + N_NODES;
    int*   blocksum   = src_sorted + E_EDGES;
    int*   blockbase  = blocksum + 512;

    hipMemsetAsync(deg, 0, N_NODES * sizeof(int), stream);

    k_deg  <<<1024, 256, 0, stream>>>(dst, deg);
    k_scan1<<<NBLK, SCAN_B, 0, stream>>>(deg, rowptr, blocksum);
    k_scan2<<<1, 512, 0, stream>>>(blocksum, blockbase, rowptr);
    k_scan3<<<NBLK, 256, 0, stream>>>(rowptr, blockbase, cursor);
    k_gemm1_scatter<<<SCB + G1B, 256, 0, stream>>>(h, W1, b1, deg, gW,
                                                   src, dst, cursor, src_sorted,
                                                   xs2, proj);
    k_aggregate<<<2048, 256, 0, stream>>>(xs2, proj, rowptr, src_sorted, gb, out);
    k_gemm2<<<G1B, 256, 0, stream>>>(out, W2, b2);
}

// Round 4
// 323.201 us; speedup vs baseline: 1.8588x; 1.4606x over previous
//
#include <hip/hip_runtime.h>
#include <hip/hip_fp16.h>
#include <math.h>

#define N_NODES 100000
#define E_EDGES 1600000
#define IN_DIM  128
#define FEAT    64
#define OUT_DIM 64
#define NBKT    391            // ceil(100000/256) buckets of 256 nodes (dst>>8)
#define CAP     6144           // per-bucket capacity in binned[] (avg 4096, 32 sigma slack)
#define RNG     4096           // edges per binscatter block
#define NSCB    ((E_EDGES + RNG - 1) / RNG)   // 391
#define G1B     ((N_NODES + 255) / 256)       // 391

// ---------------- pass A: block-local counting sort into 391 dst-buckets ----------------
// Each block sorts its 4096-edge range in LDS, then flushes per-bucket RUNS to
// global binned[] (contiguous within run -> ~no write amplification, unlike the
// old per-node random scatter which cost 16x line sharing across XCDs).
__global__ __launch_bounds__(256) void k_binscatter(
    const int* __restrict__ src, const int* __restrict__ dst,
    int* __restrict__ bucket_cursor, int* __restrict__ binned)
{
    __shared__ int hist[NBKT];
    __shared__ int baseS[NBKT + 1];
    __shared__ int cursor[NBKT];
    __shared__ int gbase[NBKT];
    __shared__ int sA[512], sB[512];
    __shared__ int buf[RNG];

    const int tid  = threadIdx.x;
    const int e0   = blockIdx.x * RNG;
    const int ecnt = min(RNG, E_EDGES - e0);

    for (int i = tid; i < NBKT; i += 256) hist[i] = 0;
    __syncthreads();

    int dsave[16];
#pragma unroll
    for (int k = 0; k < 16; ++k) {
        int e = e0 + k * 256 + tid;
        int d = (e < E_EDGES) ? dst[e] : -1;
        dsave[k] = d;
        if (d >= 0) atomicAdd(&hist[d >> 8], 1);
    }
    __syncthreads();

    // inclusive scan of hist over padded 512, double-buffered Hillis-Steele
    for (int i = tid; i < 512; i += 256) sA[i] = (i < NBKT) ? hist[i] : 0;
    __syncthreads();
    int* pa = sA; int* pb = sB;
    for (int off = 1; off < 512; off <<= 1) {
        for (int i = tid; i < 512; i += 256)
            pb[i] = pa[i] + ((i >= off) ? pa[i - off] : 0);
        __syncthreads();
        int* t = pa; pa = pb; pb = t;
    }
    for (int i = tid; i < NBKT; i += 256) {
        int ex = pa[i] - hist[i];      // exclusive
        baseS[i]  = ex;
        cursor[i] = ex;
    }
    if (tid == 0) baseS[NBKT] = ecnt;
    __syncthreads();

    // local scatter into buf (bucket-major)
#pragma unroll
    for (int k = 0; k < 16; ++k) {
        int d = dsave[k];
        if (d >= 0) {
            int e   = e0 + k * 256 + tid;
            int s   = src[e];
            int pos = atomicAdd(&cursor[d >> 8], 1);
            buf[pos] = ((d & 255) << 17) | s;   // dl:8b | src:17b
        }
    }
    __syncthreads();

    // reserve global run space per bucket
    for (int t = tid; t < NBKT; t += 256) {
        int cnt = hist[t];
        gbase[t] = cnt ? atomicAdd(&bucket_cursor[t], cnt) : 0;
    }
    __syncthreads();

    // copy runs out: element i belongs to rightmost bucket with baseS <= i
    for (int i = tid; i < ecnt; i += 256) {
        int lo = 0, hi = NBKT;
        while (hi - lo > 1) {
            int mid = (lo + hi) >> 1;
            if (baseS[mid] <= i) lo = mid; else hi = mid;
        }
        int off = gbase[lo] + (i - baseS[lo]);
        if (off < CAP) binned[lo * CAP + off] = buf[i];
    }
}

// ---------------- scan of bucket counts -> ebase (global edge base per bucket) ----------------
__global__ __launch_bounds__(512) void k_binscan(
    const int* __restrict__ bucket_cursor, int* __restrict__ ebase)
{
    __shared__ int tmp[512];
    int t = threadIdx.x;
    int v = (t < NBKT) ? bucket_cursor[t] : 0;
    tmp[t] = v;
    __syncthreads();
    for (int off = 1; off < 512; off <<= 1) {
        int add = (t >= off) ? tmp[t - off] : 0;
        __syncthreads();
        tmp[t] += add;
        __syncthreads();
    }
    if (t <= NBKT) ebase[t] = tmp[t] - v;   // exclusive; ebase[NBKT] = E
}

// ---------------- pass B: per-bucket sort -> deg, rowptr, src_sorted ----------------
// One block per 256-node bucket. rowptr comes straight from the local scan
// (+ ebase) -- no global scan kernels, no k_deg atomics. The 16KB src_sorted
// window is written by exactly one block -> full-line writeback.
__global__ __launch_bounds__(256) void k_bucketfinal(
    const int* __restrict__ binned, const int* __restrict__ ebase,
    int* __restrict__ deg, int* __restrict__ rowptr, int* __restrict__ src_sorted)
{
    __shared__ int hist[256];
    __shared__ int scn[256];
    __shared__ int cur[256];
    const int b    = blockIdx.x;
    const int tid  = threadIdx.x;
    const int eb   = ebase[b];
    const int cnt  = ebase[b + 1] - eb;
    const int base = b * CAP;

    hist[tid] = 0;
    __syncthreads();
    for (int i = tid; i < cnt; i += 256)
        atomicAdd(&hist[binned[base + i] >> 17], 1);
    __syncthreads();

    int v = hist[tid];
    scn[tid] = v;
    __syncthreads();
    for (int off = 1; off < 256; off <<= 1) {
        int add = (tid >= off) ? scn[tid - off] : 0;
        __syncthreads();
        scn[tid] += add;
        __syncthreads();
    }
    int ex = scn[tid] - v;
    cur[tid] = ex;
    int n = b * 256 + tid;
    if (n < N_NODES) {
        deg[n]    = v;
        rowptr[n] = eb + ex;
    }
    if (b == 0 && tid == 0) rowptr[N_NODES] = E_EDGES;
    __syncthreads();

    for (int i = tid; i < cnt; i += 256) {
        int p   = binned[base + i];
        int dl  = p >> 17;
        int pos = atomicAdd(&cur[dl], 1);
        src_sorted[eb + pos] = p & 0x1FFFF;
    }
}

// ---------------- gemm1: xs2h = fp16( relu(h@W1+b1) * norm ), proj = gate projections ----------------
__global__ __launch_bounds__(256, 3) void k_gemm1(
    const float* __restrict__ h, const float* __restrict__ W1,
    const float* __restrict__ b1, const int* __restrict__ deg,
    const float* __restrict__ gate_W,
    __half* __restrict__ xs2h, float* __restrict__ proj)
{
    __shared__ float Ws[IN_DIM * FEAT];   // 32 KB
    __shared__ float hT[16 * 260];        // 16.25 KB transposed tile
    const int tid = threadIdx.x;
    const int r0  = blockIdx.x * 256;

    for (int i = tid; i < IN_DIM * FEAT / 4; i += 256)
        ((float4*)Ws)[i] = ((const float4*)W1)[i];

    const int rg = tid >> 2;     // 0..63: row group (4 rows)
    const int cg = tid & 3;      // 0..3: col group == head
    const int c0 = cg * 16;
    float acc[4][16];
#pragma unroll
    for (int i = 0; i < 4; ++i)
#pragma unroll
        for (int j = 0; j < 16; ++j) acc[i][j] = 0.f;

    const int  myrow = r0 + tid;
    const bool rok   = myrow < N_NODES;

    for (int kc = 0; kc < IN_DIM / 16; ++kc) {
        float4 f[4];
        if (rok) {
            const float4* hp = (const float4*)(h + (size_t)myrow * IN_DIM + kc * 16);
            f[0] = hp[0]; f[1] = hp[1]; f[2] = hp[2]; f[3] = hp[3];
        } else {
            f[0] = f[1] = f[2] = f[3] = make_float4(0.f, 0.f, 0.f, 0.f);
        }
        __syncthreads();
#pragma unroll
        for (int q = 0; q < 4; ++q) {
            hT[(q * 4 + 0) * 260 + tid] = f[q].x;
            hT[(q * 4 + 1) * 260 + tid] = f[q].y;
            hT[(q * 4 + 2) * 260 + tid] = f[q].z;
            hT[(q * 4 + 3) * 260 + tid] = f[q].w;
        }
        __syncthreads();
#pragma unroll
        for (int kk = 0; kk < 16; ++kk) {
            float4 a4 = *(const float4*)&hT[kk * 260 + rg * 4];
            const float* wrow = &Ws[(kc * 16 + kk) * FEAT + c0];
            float4 w0 = ((const float4*)wrow)[0];
            float4 w1 = ((const float4*)wrow)[1];
            float4 w2 = ((const float4*)wrow)[2];
            float4 w3 = ((const float4*)wrow)[3];
            const float a[4] = {a4.x, a4.y, a4.z, a4.w};
            const float w[16] = {w0.x, w0.y, w0.z, w0.w, w1.x, w1.y, w1.z, w1.w,
                                 w2.x, w2.y, w2.z, w2.w, w3.x, w3.y, w3.z, w3.w};
#pragma unroll
            for (int i = 0; i < 4; ++i)
#pragma unroll
                for (int j = 0; j < 16; ++j)
                    acc[i][j] = fmaf(a[i], w[j], acc[i][j]);
        }
    }

#pragma unroll
    for (int i = 0; i < 4; ++i) {
        int r = r0 + rg * 4 + i;
        if (r >= N_NODES) continue;
        float nr = rsqrtf(fmaxf((float)deg[r], 1.f));
        float xa = 0.f, xb = 0.f;
        alignas(16) __half hv[16];
#pragma unroll
        for (int j = 0; j < 16; ++j) {
            float v = acc[i][j] + b1[c0 + j];
            v = v > 0.f ? v : 0.f;
            xa = fmaf(v, gate_W[32 + j], xa);   // dst-side gate
            xb = fmaf(v, gate_W[48 + j], xb);   // src-side gate
            hv[j] = __float2half(v * nr);
        }
        float4* xp = (float4*)(xs2h + (size_t)r * FEAT + c0);
        xp[0] = *(const float4*)&hv[0];
        xp[1] = *(const float4*)&hv[8];
        proj[(size_t)r * 8 + cg]     = xa;
        proj[(size_t)r * 8 + 4 + cg] = xb;
    }
}

// ---------------- dst-centric aggregate: v = 0.5*x + norm*sum -> d_out ----------------
__global__ __launch_bounds__(256) void k_aggregate(
    const __half* __restrict__ xs2h, const float* __restrict__ proj,
    const int* __restrict__ rowptr, const int* __restrict__ src_sorted,
    const float* __restrict__ gate_b, float* __restrict__ v_out)
{
    const int tid    = threadIdx.x;
    const int lane   = tid & 63;
    const int head   = lane >> 4;
    const int wave   = blockIdx.x * 4 + (tid >> 6);
    const int nwaves = gridDim.x * 4;
    const float gb   = gate_b[1];

    for (int n = wave; n < N_NODES; n += nwaves) {
        int beg = rowptr[n];
        int end = rowptr[n + 1];
        float a_d = proj[(size_t)n * 8 + head] + gb;
        float acc = 0.f;
        if (beg < end) {
            int last = end - 1;
            int sA = __builtin_amdgcn_readfirstlane(src_sorted[beg]);
            int sB = __builtin_amdgcn_readfirstlane(src_sorted[min(beg + 1, last)]);
            float xsv = __half2float(xs2h[(size_t)sA * FEAT + lane]);
            float bh  = proj[(size_t)sA * 8 + 4 + head];
            for (int j = beg; j < end; ++j) {
                int   sC    = __builtin_amdgcn_readfirstlane(src_sorted[min(j + 2, last)]);
                float xsv_n = __half2float(xs2h[(size_t)sB * FEAT + lane]);
                float bh_n  = proj[(size_t)sB * 8 + 4 + head];
                // tanh(p) = 1 - 2/(exp2(2*log2e*p)+1); safe at +/-inf
                float e = __builtin_amdgcn_exp2f(2.8853900817779268f * (a_d + bh));
                float t = 1.f - 2.f * __builtin_amdgcn_rcpf(e + 1.f);
                acc = fmaf(t, xsv, acc);
                xsv = xsv_n; bh = bh_n; sB = sC;
            }
        }
        float dg = fmaxf((float)(end - beg), 1.f);
        float nd = rsqrtf(dg);          // norm[n]
        float sd = dg * nd;             // sqrt(deg) = 1/norm
        float xn = __half2float(xs2h[(size_t)n * FEAT + lane]);
        float v  = fmaf(0.5f * sd, xn, acc * nd);
        v_out[(size_t)n * FEAT + lane] = v;
    }
}

// ---------------- gemm2 in-place on d_out: out = v @ W2 + b2 ----------------
__global__ __launch_bounds__(256, 3) void k_gemm2(
    float* __restrict__ v, const float* __restrict__ W2, const float* __restrict__ b2)
{
    __shared__ float Ws[FEAT * OUT_DIM];  // 16 KB
    __shared__ float vT[16 * 260];        // 16.25 KB
    const int tid = threadIdx.x;
    const int r0  = blockIdx.x * 256;

    for (int i = tid; i < FEAT * OUT_DIM / 4; i += 256)
        ((float4*)Ws)[i] = ((const float4*)W2)[i];

    const int rg = tid >> 2;
    const int cg = tid & 3;
    const int c0 = cg * 16;
    float acc[4][16];
#pragma unroll
    for (int i = 0; i < 4; ++i)
#pragma unroll
        for (int j = 0; j < 16; ++j) acc[i][j] = 0.f;

    const int  myrow = r0 + tid;
    const bool rok   = myrow < N_NODES;

    for (int kc = 0; kc < FEAT / 16; ++kc) {
        float4 f[4];
        if (rok) {
            const float4* vp = (const float4*)(v + (size_t)myrow * FEAT + kc * 16);
            f[0] = vp[0]; f[1] = vp[1]; f[2] = vp[2]; f[3] = vp[3];
        } else {
            f[0] = f[1] = f[2] = f[3] = make_float4(0.f, 0.f, 0.f, 0.f);
        }
        __syncthreads();
#pragma unroll
        for (int q = 0; q < 4; ++q) {
            vT[(q * 4 + 0) * 260 + tid] = f[q].x;
            vT[(q * 4 + 1) * 260 + tid] = f[q].y;
            vT[(q * 4 + 2) * 260 + tid] = f[q].z;
            vT[(q * 4 + 3) * 260 + tid] = f[q].w;
        }
        __syncthreads();
#pragma unroll
        for (int kk = 0; kk < 16; ++kk) {
            float4 a4 = *(const float4*)&vT[kk * 260 + rg * 4];
            const float* wrow = &Ws[(kc * 16 + kk) * OUT_DIM + c0];
            float4 w0 = ((const float4*)wrow)[0];
            float4 w1 = ((const float4*)wrow)[1];
            float4 w2 = ((const float4*)wrow)[2];
            float4 w3 = ((const float4*)wrow)[3];
            const float a[4] = {a4.x, a4.y, a4.z, a4.w};
            const float w[16] = {w0.x, w0.y, w0.z, w0.w, w1.x, w1.y, w1.z, w1.w,
                                 w2.x, w2.y, w2.z, w2.w, w3.x, w3.y, w3.z, w3.w};
#pragma unroll
            for (int i = 0; i < 4; ++i)
#pragma unroll
                for (int j = 0; j < 16; ++j)
                    acc[i][j] = fmaf(a[i], w[j], acc[i][j]);
        }
    }

#pragma unroll
    for (int i = 0; i < 4; ++i) {
        int r = r0 + rg * 4 + i;
        if (r >= N_NODES) continue;
        float* op = &v[(size_t)r * OUT_DIM + c0];
#pragma unroll
        for (int q = 0; q < 4; ++q) {
            float4 o = make_float4(acc[i][q*4]   + b2[c0 + q*4],
                                   acc[i][q*4+1] + b2[c0 + q*4 + 1],
                                   acc[i][q*4+2] + b2[c0 + q*4 + 2],
                                   acc[i][q*4+3] + b2[c0 + q*4 + 3]);
            ((float4*)op)[q] = o;
        }
    }
}

extern "C" void kernel_launch(void* const* d_in, const int* in_sizes, int n_in,
                              void* d_out, int out_size, void* d_ws, size_t ws_size,
                              hipStream_t stream)
{
    const float* h   = (const float*)d_in[0];
    const int*   src = (const int*)d_in[1];
    const int*   dst = (const int*)d_in[2];
    const float* W1  = (const float*)d_in[3];
    const float* b1  = (const float*)d_in[4];
    const float* W2  = (const float*)d_in[5];
    const float* b2  = (const float*)d_in[6];
    const float* gW  = (const float*)d_in[7];
    const float* gb  = (const float*)d_in[8];
    float* out = (float*)d_out;

    // ws (ints first): binned[NBKT*CAP] | src_sorted[E] | rowptr[N+1] | deg[N]
    //                  | bucket_cursor[NBKT] | ebase[NBKT+1] | proj[N*8] f32 | xs2h[N*64] f16
    int* binned        = (int*)d_ws;
    int* src_sorted    = binned + (size_t)NBKT * CAP;
    int* rowptr        = src_sorted + E_EDGES;
    int* deg           = rowptr + (N_NODES + 1);
    int* bucket_cursor = deg + N_NODES;
    int* ebase         = bucket_cursor + NBKT;
    float* proj        = (float*)(ebase + (NBKT + 1));
    __half* xs2h       = (__half*)(proj + (size_t)N_NODES * 8);

    hipMemsetAsync(bucket_cursor, 0, NBKT * sizeof(int), stream);

    k_binscatter <<<NSCB, 256, 0, stream>>>(src, dst, bucket_cursor, binned);
    k_binscan    <<<1, 512, 0, stream>>>(bucket_cursor, ebase);
    k_bucketfinal<<<NBKT, 256, 0, stream>>>(binned, ebase, deg, rowptr, src_sorted);
    k_gemm1      <<<G1B, 256, 0, stream>>>(h, W1, b1, deg, gW, xs2h, proj);
    k_aggregate  <<<2048, 256, 0, stream>>>(xs2h, proj, rowptr, src_sorted, gb, out);
    k_gemm2      <<<G1B, 256, 0, stream>>>(out, W2, b2);
}